// Round 1
// baseline (221.589 us; speedup 1.0000x reference)
//
#include <hip/hip_runtime.h>
#include <hip/hip_bf16.h>
#include <stdint.h>

// Problem constants
#define EXP 8
#define DIM 1024
#define SEQL 512
#define BATCH 8
#define OUT_FINAL_N (BATCH * SEQL * DIM)   // 4194304
#define OFF_AUX    4194304
#define OFF_MASK   4194305
#define OFF_LOGITS 4194369

typedef __bf16 bf16_t;
typedef bf16_t bf16x8 __attribute__((ext_vector_type(8)));
typedef bf16_t bf16x4 __attribute__((ext_vector_type(4)));
typedef float  f32x4  __attribute__((ext_vector_type(4)));

typedef __attribute__((address_space(1))) void* as1p;
typedef __attribute__((address_space(3))) void* as3p;

__device__ __forceinline__ void glds16(const void* g, void* l) {
  // async global->LDS, 16B per lane; LDS dest must be wave-uniform base + lane*16
  __builtin_amdgcn_global_load_lds((as1p)(void*)g, (as3p)l, 16, 0, 0);
}

// ---------------------------------------------------------------------------
// Router: logits = dec @ rw^T + rb; softmax; top-2; mask; aux loss.
// One block, 256 threads. 4 threads per (b,e) pair.
// ---------------------------------------------------------------------------
__global__ void router_kernel(const float* __restrict__ dec,
                              const float* __restrict__ rw,
                              const float* __restrict__ rb,
                              float* __restrict__ out_aux,
                              float* __restrict__ out_mask,
                              float* __restrict__ out_logits,
                              int* __restrict__ idx_ws,
                              float* __restrict__ w_ws) {
  __shared__ float part[256];
  __shared__ float lg[64];
  __shared__ float probs[64];
  __shared__ float msk[64];
  const int tid = threadIdx.x;
  const int p = tid >> 2, seg = tid & 3;
  const int b = p >> 3, e = p & 7;
  const float4* dv = (const float4*)(dec + b * DIM + seg * 256);
  const float4* wv = (const float4*)(rw + e * DIM + seg * 256);
  float s = 0.f;
#pragma unroll 8
  for (int i = 0; i < 64; ++i) {
    float4 a = dv[i], c = wv[i];
    s += a.x * c.x + a.y * c.y + a.z * c.z + a.w * c.w;
  }
  part[tid] = s;
  __syncthreads();
  if (seg == 0) {
    float l = part[tid] + part[tid + 1] + part[tid + 2] + part[tid + 3] + rb[e];
    lg[p] = l;
    out_logits[p] = l;
  }
  __syncthreads();
  if (tid < 8) {  // one thread per batch row
    float l[8];
    float mx = -1e30f;
#pragma unroll
    for (int k = 0; k < 8; ++k) { l[k] = lg[tid * 8 + k]; mx = fmaxf(mx, l[k]); }
    float pe[8];
    float sum = 0.f;
#pragma unroll
    for (int k = 0; k < 8; ++k) { pe[k] = expf(l[k] - mx); sum += pe[k]; }
    float inv = 1.f / sum;
#pragma unroll
    for (int k = 0; k < 8; ++k) { pe[k] *= inv; probs[tid * 8 + k] = pe[k]; }
    // top-2 (strict > keeps lowest index on ties, matching lax.top_k)
    int i0 = 0;
#pragma unroll
    for (int k = 1; k < 8; ++k) if (pe[k] > pe[i0]) i0 = k;
    int i1 = (i0 == 0) ? 1 : 0;
#pragma unroll
    for (int k = 0; k < 8; ++k) if (k != i0 && pe[k] > pe[i1]) i1 = k;
    float p0 = pe[i0], p1 = pe[i1];
    float invs = 1.f / (p0 + p1);
    idx_ws[tid * 2] = i0;
    idx_ws[tid * 2 + 1] = i1;
    w_ws[tid * 2] = p0 * invs;
    w_ws[tid * 2 + 1] = p1 * invs;
#pragma unroll
    for (int k = 0; k < 8; ++k) {
      float m = (k == i0 || k == i1) ? 1.f : 0.f;
      msk[tid * 8 + k] = m;
      out_mask[tid * 8 + k] = m;
    }
  }
  __syncthreads();
  if (tid == 0) {
    float aux = 0.f;
#pragma unroll
    for (int k = 0; k < 8; ++k) {
      float mp = 0.f, mm = 0.f;
#pragma unroll
      for (int bb = 0; bb < 8; ++bb) { mp += probs[bb * 8 + k]; mm += msk[bb * 8 + k]; }
      aux += (mp * 0.125f) * (mm * 0.125f);
    }
    out_aux[0] = 8.f * aux;
  }
}

// ---------------------------------------------------------------------------
// Cast x (fp32) -> bf16, vectorized float4 -> bf16x4
// ---------------------------------------------------------------------------
__global__ void cast_x_kernel(const float* __restrict__ x, bf16_t* __restrict__ xb) {
  const int i = blockIdx.x * 256 + threadIdx.x;  // exact: 4096*256 = 1048576 float4s
  float4 v = ((const float4*)x)[i];
  bf16x4 o;
  o[0] = (bf16_t)v.x; o[1] = (bf16_t)v.y; o[2] = (bf16_t)v.z; o[3] = (bf16_t)v.w;
  ((bf16x4*)xb)[i] = o;
}

// ---------------------------------------------------------------------------
// Transpose-cast weights: w (E,K,N) fp32 -> wt (E,N,K) bf16.  z<8: w1, else w2.
// 32x32 fp32 LDS tile, block (32,8).
// ---------------------------------------------------------------------------
__global__ void transpose_cast_kernel(const float* __restrict__ w1,
                                      const float* __restrict__ w2,
                                      bf16_t* __restrict__ w1t,
                                      bf16_t* __restrict__ w2t) {
  __shared__ float tile[32][33];
  const int z = blockIdx.z;
  const float* src = (z < 8) ? (w1 + (size_t)z * DIM * DIM) : (w2 + (size_t)(z - 8) * DIM * DIM);
  bf16_t* dst = (z < 8) ? (w1t + (size_t)z * DIM * DIM) : (w2t + (size_t)(z - 8) * DIM * DIM);
  const int tx = threadIdx.x, ty = threadIdx.y;
  const int c0 = blockIdx.x * 32, r0 = blockIdx.y * 32;
#pragma unroll
  for (int j = 0; j < 32; j += 8) tile[ty + j][tx] = src[(size_t)(r0 + ty + j) * DIM + c0 + tx];
  __syncthreads();
#pragma unroll
  for (int j = 0; j < 32; j += 8)
    dst[(size_t)(c0 + ty + j) * DIM + r0 + tx] = (bf16_t)tile[tx][ty + j];
}

// ---------------------------------------------------------------------------
// Shared MFMA K-loop core (m97 structure):
// C[128x128] tile, BK=32, block = 256 thr = 4 waves (2x2), wave = 64x64 =
// 4x4 tiles of mfma_f32_16x16x32_bf16.  A (M,K) K-major, Bt (N,K) K-major.
// LDS: As[128][32]b16 (8KB) + Bs[128][32] (8KB), 16B chunks XOR-swizzled by
// (row&3) so ds_read_b128 fragment reads are ~2-way (free) instead of 8-way.
// Staged with global_load_lds dwordx4 (2 issues per tile per operand).
// ---------------------------------------------------------------------------
__device__ __forceinline__ void gemm_kloop(const bf16_t* __restrict__ A,
                                           const bf16_t* __restrict__ Bt,
                                           char* sA, char* sB,
                                           int tid, f32x4 acc[4][4]) {
  const int lane = tid & 63;
  const int w = tid >> 6;
  const int wr = w >> 1, wc = w & 1;
  const int m15 = lane & 15, q = lane >> 4;

  // staging: lane covers (row rl, chunk-pos tid&3); data chunk c = pos ^ (rl&3)
  const int rl = tid >> 2;
  const int cp = (tid & 3) ^ (rl & 3);
  const bf16_t* ga0 = A + (size_t)rl * DIM + cp * 8;
  const bf16_t* ga1 = ga0 + (size_t)64 * DIM;
  const bf16_t* gb0 = Bt + (size_t)rl * DIM + cp * 8;
  const bf16_t* gb1 = gb0 + (size_t)64 * DIM;
  char* la0 = sA + tid * 16;
  char* la1 = sA + 4096 + tid * 16;
  char* lb0 = sB + tid * 16;
  char* lb1 = sB + 4096 + tid * 16;

  // fragment read addresses (A: m = lane&15, k-chunk = quad; swizzled)
  const char* ra[4];
  const char* rb[4];
#pragma unroll
  for (int i = 0; i < 4; ++i) {
    int r = wr * 64 + i * 16 + m15;
    ra[i] = sA + r * 64 + ((q ^ (r & 3)) * 16);
    int n = wc * 64 + i * 16 + m15;
    rb[i] = sB + n * 64 + ((q ^ (n & 3)) * 16);
  }

  for (int kt = 0; kt < DIM; kt += 32) {
    glds16(ga0 + kt, la0);
    glds16(ga1 + kt, la1);
    glds16(gb0 + kt, lb0);
    glds16(gb1 + kt, lb1);
    __syncthreads();  // barrier drains vmcnt -> LDS tile complete
    bf16x8 af[4], bfr[4];
#pragma unroll
    for (int i = 0; i < 4; ++i) af[i] = *(const bf16x8*)ra[i];
#pragma unroll
    for (int j = 0; j < 4; ++j) bfr[j] = *(const bf16x8*)rb[j];
#pragma unroll
    for (int i = 0; i < 4; ++i)
#pragma unroll
      for (int j = 0; j < 4; ++j)
        acc[i][j] = __builtin_amdgcn_mfma_f32_16x16x32_bf16(af[i], bfr[j], acc[i][j], 0, 0, 0);
    __syncthreads();  // all reads done before next-tile overwrite
  }
}

// ---------------------------------------------------------------------------
// GEMM1: hidden[slot] = relu(x[b] @ w1[e] + b1[e]), bf16 out.
// grid (8, 4, 16): (Ntile, Mtile, slot=b*2+k)
// ---------------------------------------------------------------------------
__global__ __launch_bounds__(256) void gemm1_kernel(const bf16_t* __restrict__ xb,
                                                    const bf16_t* __restrict__ w1t,
                                                    const float* __restrict__ b1,
                                                    const int* __restrict__ topk_idx,
                                                    bf16_t* __restrict__ hidden) {
  __shared__ __align__(16) char smem[16384];
  const int tid = threadIdx.x;
  const int bN = blockIdx.x, bM = blockIdx.y, slot = blockIdx.z;
  const int b = slot >> 1;
  const int e = topk_idx[slot];

  const bf16_t* A = xb + ((size_t)b * SEQL + bM * 128) * DIM;
  const bf16_t* Bt = w1t + ((size_t)e * DIM + bN * 128) * DIM;

  f32x4 acc[4][4];
#pragma unroll
  for (int i = 0; i < 4; ++i)
#pragma unroll
    for (int j = 0; j < 4; ++j) acc[i][j] = {0.f, 0.f, 0.f, 0.f};

  gemm_kloop(A, Bt, smem, smem + 8192, tid, acc);

  // epilogue: C/D layout col=lane&15, row=quad*4+reg (m89-verified)
  const int lane = tid & 63, w = tid >> 6;
  const int wr = w >> 1, wc = w & 1;
  const int m15 = lane & 15, q = lane >> 4;
  const float* be = b1 + e * DIM;
  bf16_t* H = hidden + (size_t)slot * SEQL * DIM;
#pragma unroll
  for (int i = 0; i < 4; ++i) {
    int row = bM * 128 + wr * 64 + i * 16 + q * 4;
#pragma unroll
    for (int j = 0; j < 4; ++j) {
      int col = bN * 128 + wc * 64 + j * 16 + m15;
      float bias = be[col];
#pragma unroll
      for (int r = 0; r < 4; ++r) {
        float v = acc[i][j][r] + bias;
        H[(size_t)(row + r) * DIM + col] = (bf16_t)fmaxf(v, 0.f);
      }
    }
  }
}

// ---------------------------------------------------------------------------
// GEMM2: out[b] = w0*(h0 @ w2[e0] + b2[e0]) + w1*(h1 @ w2[e1] + b2[e1]), fp32.
// Both expert contributions in one block (no atomics): acc trick
//   acc = gemm(e0); acc *= w0/w1; acc += gemm(e1); out = w1*acc + biases.
// grid (8, 4, 8): (Ntile, Mtile, batch)
// ---------------------------------------------------------------------------
__global__ __launch_bounds__(256) void gemm2_kernel(const bf16_t* __restrict__ hidden,
                                                    const bf16_t* __restrict__ w2t,
                                                    const float* __restrict__ b2,
                                                    const int* __restrict__ topk_idx,
                                                    const float* __restrict__ topk_w,
                                                    float* __restrict__ out) {
  __shared__ __align__(16) char smem[16384];
  const int tid = threadIdx.x;
  const int bN = blockIdx.x, bM = blockIdx.y, b = blockIdx.z;
  const int e0 = topk_idx[b * 2], e1 = topk_idx[b * 2 + 1];
  const float w0 = topk_w[b * 2], w1v = topk_w[b * 2 + 1];

  f32x4 acc[4][4];
#pragma unroll
  for (int i = 0; i < 4; ++i)
#pragma unroll
    for (int j = 0; j < 4; ++j) acc[i][j] = {0.f, 0.f, 0.f, 0.f};

  const bf16_t* A0 = hidden + ((size_t)(b * 2) * SEQL + bM * 128) * DIM;
  const bf16_t* B0 = w2t + ((size_t)e0 * DIM + bN * 128) * DIM;
  gemm_kloop(A0, B0, smem, smem + 8192, tid, acc);

  const float s = w0 / w1v;  // w1v > 0 (softmax probs strictly positive)
#pragma unroll
  for (int i = 0; i < 4; ++i)
#pragma unroll
    for (int j = 0; j < 4; ++j) acc[i][j] *= s;

  const bf16_t* A1 = hidden + ((size_t)(b * 2 + 1) * SEQL + bM * 128) * DIM;
  const bf16_t* B1 = w2t + ((size_t)e1 * DIM + bN * 128) * DIM;
  gemm_kloop(A1, B1, smem, smem + 8192, tid, acc);

  const int lane = tid & 63, w = tid >> 6;
  const int wr = w >> 1, wc = w & 1;
  const int m15 = lane & 15, q = lane >> 4;
  const float* be0 = b2 + e0 * DIM;
  const float* be1 = b2 + e1 * DIM;
  float* O = out + (size_t)b * SEQL * DIM;
#pragma unroll
  for (int i = 0; i < 4; ++i) {
    int row = bM * 128 + wr * 64 + i * 16 + q * 4;
#pragma unroll
    for (int j = 0; j < 4; ++j) {
      int col = bN * 128 + wc * 64 + j * 16 + m15;
      float bb = w0 * be0[col] + w1v * be1[col];
#pragma unroll
      for (int r = 0; r < 4; ++r) {
        O[(size_t)(row + r) * DIM + col] = w1v * acc[i][j][r] + bb;
      }
    }
  }
}

// ---------------------------------------------------------------------------
extern "C" void kernel_launch(void* const* d_in, const int* in_sizes, int n_in,
                              void* d_out, int out_size, void* d_ws, size_t ws_size,
                              hipStream_t stream) {
  const float* x   = (const float*)d_in[0];
  const float* dec = (const float*)d_in[1];
  const float* rw  = (const float*)d_in[2];
  const float* rb  = (const float*)d_in[3];
  const float* w1  = (const float*)d_in[4];
  const float* w2  = (const float*)d_in[5];
  const float* b1  = (const float*)d_in[6];
  const float* b2  = (const float*)d_in[7];
  float* out = (float*)d_out;

  // ws layout: xb 8MB | w1t 16MB | w2t 16MB | hidden 16MB | router scratch
  char* ws = (char*)d_ws;
  bf16_t* xb   = (bf16_t*)(ws);
  bf16_t* w1t  = (bf16_t*)(ws + (8u << 20));
  bf16_t* w2t  = (bf16_t*)(ws + (24u << 20));
  bf16_t* hid  = (bf16_t*)(ws + (40u << 20));
  int*    idxw = (int*)(ws + (56u << 20));
  float*  ww   = (float*)(ws + (56u << 20) + 64);

  hipLaunchKernelGGL(router_kernel, dim3(1), dim3(256), 0, stream,
                     dec, rw, rb, out + OFF_AUX, out + OFF_MASK, out + OFF_LOGITS, idxw, ww);
  hipLaunchKernelGGL(cast_x_kernel, dim3(4096), dim3(256), 0, stream, x, xb);
  hipLaunchKernelGGL(transpose_cast_kernel, dim3(32, 32, 16), dim3(32, 8), 0, stream,
                     w1, w2, w1t, w2t);
  hipLaunchKernelGGL(gemm1_kernel, dim3(8, 4, 16), dim3(256), 0, stream,
                     xb, w1t, b1, idxw, hid);
  hipLaunchKernelGGL(gemm2_kernel, dim3(8, 4, 8), dim3(256), 0, stream,
                     hid, w2t, b2, idxw, ww, out);
}

// Round 2
// 206.879 us; speedup vs baseline: 1.0711x; 1.0711x over previous
//
#include <hip/hip_runtime.h>
#include <hip/hip_bf16.h>
#include <stdint.h>

// Problem constants
#define EXP 8
#define DIM 1024
#define SEQL 512
#define BATCH 8
#define OUT_FINAL_N (BATCH * SEQL * DIM)   // 4194304
#define OFF_AUX    4194304
#define OFF_MASK   4194305
#define OFF_LOGITS 4194369

typedef __bf16 bf16_t;
typedef bf16_t bf16x8 __attribute__((ext_vector_type(8)));
typedef bf16_t bf16x4 __attribute__((ext_vector_type(4)));
typedef float  f32x4  __attribute__((ext_vector_type(4)));

typedef __attribute__((address_space(1))) void* as1p;
typedef __attribute__((address_space(3))) void* as3p;

__device__ __forceinline__ void glds16(const void* g, void* l) {
  // async global->LDS, 16B per lane; LDS dest must be wave-uniform base + lane*16
  __builtin_amdgcn_global_load_lds((as1p)(void*)g, (as3p)l, 16, 0, 0);
}

// ---------------------------------------------------------------------------
// prep_kernel: fused { weight transpose-cast | x cast | router }.
// grid.x = 4096 (transpose, 64x64 tiles) + 1024 (cast) + 1 (router), 256 thr.
// ---------------------------------------------------------------------------
__global__ __launch_bounds__(256) void prep_kernel(
    const float* __restrict__ x, const float* __restrict__ dec,
    const float* __restrict__ rw, const float* __restrict__ rb,
    const float* __restrict__ w1, const float* __restrict__ w2,
    bf16_t* __restrict__ xb, bf16_t* __restrict__ w1t, bf16_t* __restrict__ w2t,
    float* __restrict__ out_aux, float* __restrict__ out_mask,
    float* __restrict__ out_logits, int* __restrict__ idx_ws,
    float* __restrict__ w_ws) {
  __shared__ float tile[64][65];     // transpose staging (16.6 KB)
  __shared__ float part[256];        // router scratch
  __shared__ float lg64[64];
  __shared__ float probs[64];
  __shared__ float msk[64];
  const int bid = blockIdx.x;
  const int t = threadIdx.x;

  if (bid < 4096) {
    // ---- transpose-cast: matrix z (z<8: w1, else w2), 64x64 tile ----
    const int z = bid >> 8;
    const int rem = bid & 255;
    const int r0 = (rem >> 4) * 64, c0 = (rem & 15) * 64;
    const float* src = (z < 8) ? (w1 + (size_t)z * DIM * DIM)
                               : (w2 + (size_t)(z - 8) * DIM * DIM);
    bf16_t* dst = (z < 8) ? (w1t + (size_t)z * DIM * DIM)
                          : (w2t + (size_t)(z - 8) * DIM * DIM);
    const int rr = t >> 4, cc = t & 15;
#pragma unroll
    for (int i = 0; i < 4; ++i) {
      const int row = rr + i * 16;
      const float4 v = *(const float4*)(src + (size_t)(r0 + row) * DIM + c0 + cc * 4);
      tile[row][cc * 4 + 0] = v.x;   // stride-65 rows: 2-way bank alias (free)
      tile[row][cc * 4 + 1] = v.y;
      tile[row][cc * 4 + 2] = v.z;
      tile[row][cc * 4 + 3] = v.w;
    }
    __syncthreads();
#pragma unroll
    for (int i = 0; i < 4; ++i) {
      const int dc = rr + i * 16;    // dst row = orig col
      bf16x4 o;
      o[0] = (bf16_t)tile[cc * 4 + 0][dc];
      o[1] = (bf16_t)tile[cc * 4 + 1][dc];
      o[2] = (bf16_t)tile[cc * 4 + 2][dc];
      o[3] = (bf16_t)tile[cc * 4 + 3][dc];
      *(bf16x4*)(dst + (size_t)(c0 + dc) * DIM + r0 + cc * 4) = o;
    }
  } else if (bid < 4096 + 1024) {
    // ---- cast x: 1M float4s over 1024 blocks, 4 per thread ----
    const int i0 = (bid - 4096) * 1024 + t;
#pragma unroll
    for (int i = 0; i < 4; ++i) {
      float4 v = ((const float4*)x)[i0 + i * 256];
      bf16x4 o;
      o[0] = (bf16_t)v.x; o[1] = (bf16_t)v.y; o[2] = (bf16_t)v.z; o[3] = (bf16_t)v.w;
      ((bf16x4*)xb)[i0 + i * 256] = o;
    }
  } else {
    // ---- router ----
    const int p = t >> 2, seg = t & 3;
    const int b = p >> 3, e = p & 7;
    const float4* dv = (const float4*)(dec + b * DIM + seg * 256);
    const float4* wv = (const float4*)(rw + e * DIM + seg * 256);
    float s = 0.f;
#pragma unroll 8
    for (int i = 0; i < 64; ++i) {
      float4 a = dv[i], c = wv[i];
      s += a.x * c.x + a.y * c.y + a.z * c.z + a.w * c.w;
    }
    part[t] = s;
    __syncthreads();
    if (seg == 0) {
      float l = part[t] + part[t + 1] + part[t + 2] + part[t + 3] + rb[e];
      lg64[p] = l;
      out_logits[p] = l;
    }
    __syncthreads();
    if (t < 8) {
      float l[8];
      float mx = -1e30f;
#pragma unroll
      for (int k = 0; k < 8; ++k) { l[k] = lg64[t * 8 + k]; mx = fmaxf(mx, l[k]); }
      float pe[8];
      float sum = 0.f;
#pragma unroll
      for (int k = 0; k < 8; ++k) { pe[k] = expf(l[k] - mx); sum += pe[k]; }
      float inv = 1.f / sum;
#pragma unroll
      for (int k = 0; k < 8; ++k) { pe[k] *= inv; probs[t * 8 + k] = pe[k]; }
      int i0 = 0;
#pragma unroll
      for (int k = 1; k < 8; ++k) if (pe[k] > pe[i0]) i0 = k;
      int i1 = (i0 == 0) ? 1 : 0;
#pragma unroll
      for (int k = 0; k < 8; ++k) if (k != i0 && pe[k] > pe[i1]) i1 = k;
      float p0 = pe[i0], p1 = pe[i1];
      float invs = 1.f / (p0 + p1);
      idx_ws[t * 2] = i0;
      idx_ws[t * 2 + 1] = i1;
      w_ws[t * 2] = p0 * invs;
      w_ws[t * 2 + 1] = p1 * invs;
#pragma unroll
      for (int k = 0; k < 8; ++k) {
        float m = (k == i0 || k == i1) ? 1.f : 0.f;
        msk[t * 8 + k] = m;
        out_mask[t * 8 + k] = m;
      }
    }
    __syncthreads();
    if (t == 0) {
      float aux = 0.f;
#pragma unroll
      for (int k = 0; k < 8; ++k) {
        float mp = 0.f, mm = 0.f;
#pragma unroll
        for (int bb = 0; bb < 8; ++bb) { mp += probs[bb * 8 + k]; mm += msk[bb * 8 + k]; }
        aux += (mp * 0.125f) * (mm * 0.125f);
      }
      out_aux[0] = 8.f * aux;
    }
  }
}

// ---------------------------------------------------------------------------
// Shared MFMA K-loop core (m97 structure):
// C[128x128] tile, BK=32, 4 waves (2x2), wave = 64x64 = 4x4 tiles of
// mfma_f32_16x16x32_bf16.  A (M,K) K-major, Bt (N,K) K-major.
// LDS: As[128][32]b16 (8KB) + Bs[128][32] (8KB), 16B chunks XOR-swizzled.
// tid must be the 0..255 index of the participating 4-wave group.
// ---------------------------------------------------------------------------
__device__ __forceinline__ void gemm_kloop(const bf16_t* __restrict__ A,
                                           const bf16_t* __restrict__ Bt,
                                           char* sA, char* sB,
                                           int tid, f32x4 acc[4][4]) {
  const int lane = tid & 63;
  const int w = tid >> 6;
  const int wr = w >> 1, wc = w & 1;
  const int m15 = lane & 15, q = lane >> 4;

  const int rl = tid >> 2;
  const int cp = (tid & 3) ^ (rl & 3);
  const bf16_t* ga0 = A + (size_t)rl * DIM + cp * 8;
  const bf16_t* ga1 = ga0 + (size_t)64 * DIM;
  const bf16_t* gb0 = Bt + (size_t)rl * DIM + cp * 8;
  const bf16_t* gb1 = gb0 + (size_t)64 * DIM;
  char* la0 = sA + tid * 16;
  char* la1 = sA + 4096 + tid * 16;
  char* lb0 = sB + tid * 16;
  char* lb1 = sB + 4096 + tid * 16;

  const char* ra[4];
  const char* rb[4];
#pragma unroll
  for (int i = 0; i < 4; ++i) {
    int r = wr * 64 + i * 16 + m15;
    ra[i] = sA + r * 64 + ((q ^ (r & 3)) * 16);
    int n = wc * 64 + i * 16 + m15;
    rb[i] = sB + n * 64 + ((q ^ (n & 3)) * 16);
  }

  for (int kt = 0; kt < DIM; kt += 32) {
    glds16(ga0 + kt, la0);
    glds16(ga1 + kt, la1);
    glds16(gb0 + kt, lb0);
    glds16(gb1 + kt, lb1);
    __syncthreads();
    bf16x8 af[4], bfr[4];
#pragma unroll
    for (int i = 0; i < 4; ++i) af[i] = *(const bf16x8*)ra[i];
#pragma unroll
    for (int j = 0; j < 4; ++j) bfr[j] = *(const bf16x8*)rb[j];
#pragma unroll
    for (int i = 0; i < 4; ++i)
#pragma unroll
      for (int j = 0; j < 4; ++j)
        acc[i][j] = __builtin_amdgcn_mfma_f32_16x16x32_bf16(af[i], bfr[j], acc[i][j], 0, 0, 0);
    __syncthreads();
  }
}

// ---------------------------------------------------------------------------
// GEMM1: hidden[slot] = relu(x[b] @ w1[e] + b1[e]), bf16 out.
// grid (8, 4, 16): (Ntile, Mtile, slot=b*2+k), 256 threads.
// ---------------------------------------------------------------------------
__global__ __launch_bounds__(256) void gemm1_kernel(const bf16_t* __restrict__ xb,
                                                    const bf16_t* __restrict__ w1t,
                                                    const float* __restrict__ b1,
                                                    const int* __restrict__ topk_idx,
                                                    bf16_t* __restrict__ hidden) {
  __shared__ __align__(16) char smem[16384];
  const int tid = threadIdx.x;
  const int bN = blockIdx.x, bM = blockIdx.y, slot = blockIdx.z;
  const int b = slot >> 1;
  const int e = topk_idx[slot];

  const bf16_t* A = xb + ((size_t)b * SEQL + bM * 128) * DIM;
  const bf16_t* Bt = w1t + ((size_t)e * DIM + bN * 128) * DIM;

  f32x4 acc[4][4];
#pragma unroll
  for (int i = 0; i < 4; ++i)
#pragma unroll
    for (int j = 0; j < 4; ++j) acc[i][j] = {0.f, 0.f, 0.f, 0.f};

  gemm_kloop(A, Bt, smem, smem + 8192, tid, acc);

  // epilogue: C/D layout col=lane&15, row=quad*4+reg (m89-verified)
  const int lane = tid & 63, w = tid >> 6;
  const int wr = w >> 1, wc = w & 1;
  const int m15 = lane & 15, q = lane >> 4;
  const float* be = b1 + e * DIM;
  bf16_t* H = hidden + (size_t)slot * SEQL * DIM;
#pragma unroll
  for (int i = 0; i < 4; ++i) {
    int row = bM * 128 + wr * 64 + i * 16 + q * 4;
#pragma unroll
    for (int j = 0; j < 4; ++j) {
      int col = bN * 128 + wc * 64 + j * 16 + m15;
      float bias = be[col];
#pragma unroll
      for (int r = 0; r < 4; ++r) {
        float v = acc[i][j][r] + bias;
        H[(size_t)(row + r) * DIM + col] = (bf16_t)fmaxf(v, 0.f);
      }
    }
  }
}

// ---------------------------------------------------------------------------
// GEMM2 v2: both experts concurrently. 512 thr = 2 groups x 4 waves.
// Group g computes sg*(h_g @ w2[e_g]); group1 passes its scaled acc through
// LDS (stride-256 scratch -> bank = t%32, conflict-free); group0 adds biases
// and stores fp32.  grid (8, 4, 8): (Ntile, Mtile, batch).
// ---------------------------------------------------------------------------
__global__ __launch_bounds__(512) void gemm2_kernel(const bf16_t* __restrict__ hidden,
                                                    const bf16_t* __restrict__ w2t,
                                                    const float* __restrict__ b2,
                                                    const int* __restrict__ topk_idx,
                                                    const float* __restrict__ topk_w,
                                                    float* __restrict__ out) {
  __shared__ __align__(16) char smem[32768];
  const int tid = threadIdx.x;
  const int g = tid >> 8;        // expert slot group
  const int t = tid & 255;       // index within group
  const int bN = blockIdx.x, bM = blockIdx.y, b = blockIdx.z;
  const int e = topk_idx[b * 2 + g];
  const float sg = topk_w[b * 2 + g];

  char* sA = smem + g * 16384;
  char* sB = smem + g * 16384 + 8192;

  f32x4 acc[4][4];
#pragma unroll
  for (int i = 0; i < 4; ++i)
#pragma unroll
    for (int j = 0; j < 4; ++j) acc[i][j] = {0.f, 0.f, 0.f, 0.f};

  const bf16_t* A = hidden + ((size_t)(b * 2 + g) * SEQL + bM * 128) * DIM;
  const bf16_t* Bt = w2t + ((size_t)e * DIM + bN * 128) * DIM;
  gemm_kloop(A, Bt, sA, sB, t, acc);

  // ---- combine: group1 -> LDS -> group0 adds + biases + store ----
  float* scr = (float*)smem;     // 32 KB = 8192 floats = one i-half per pass
  const int lane = t & 63, wv = t >> 6;
  const int wr = wv >> 1, wc = wv & 1;
  const int m15 = lane & 15, q = lane >> 4;
  const float w0 = topk_w[b * 2], w1v = topk_w[b * 2 + 1];
  const float* be0 = b2 + topk_idx[b * 2] * DIM;
  const float* be1 = b2 + topk_idx[b * 2 + 1] * DIM;
  float* O = out + (size_t)b * SEQL * DIM;

#pragma unroll
  for (int half = 0; half < 2; ++half) {
    __syncthreads();             // staging buffers / prev-half reads done
    if (g == 1) {
#pragma unroll
      for (int ii = 0; ii < 2; ++ii)
#pragma unroll
        for (int j = 0; j < 4; ++j)
#pragma unroll
          for (int r = 0; r < 4; ++r)
            scr[(ii * 16 + j * 4 + r) * 256 + t] = sg * acc[half * 2 + ii][j][r];
    }
    __syncthreads();
    if (g == 0) {
#pragma unroll
      for (int ii = 0; ii < 2; ++ii) {
        const int i = half * 2 + ii;
        const int row = bM * 128 + wr * 64 + i * 16 + q * 4;
#pragma unroll
        for (int j = 0; j < 4; ++j) {
          const int col = bN * 128 + wc * 64 + j * 16 + m15;
          const float bb = w0 * be0[col] + w1v * be1[col];
#pragma unroll
          for (int r = 0; r < 4; ++r) {
            O[(size_t)(row + r) * DIM + col] =
                sg * acc[i][j][r] + scr[(ii * 16 + j * 4 + r) * 256 + t] + bb;
          }
        }
      }
    }
  }
}

// ---------------------------------------------------------------------------
extern "C" void kernel_launch(void* const* d_in, const int* in_sizes, int n_in,
                              void* d_out, int out_size, void* d_ws, size_t ws_size,
                              hipStream_t stream) {
  const float* x   = (const float*)d_in[0];
  const float* dec = (const float*)d_in[1];
  const float* rw  = (const float*)d_in[2];
  const float* rb  = (const float*)d_in[3];
  const float* w1  = (const float*)d_in[4];
  const float* w2  = (const float*)d_in[5];
  const float* b1  = (const float*)d_in[6];
  const float* b2  = (const float*)d_in[7];
  float* out = (float*)d_out;

  // ws layout: xb 8MB | w1t 16MB | w2t 16MB | hidden 16MB | router scratch
  char* ws = (char*)d_ws;
  bf16_t* xb   = (bf16_t*)(ws);
  bf16_t* w1t  = (bf16_t*)(ws + (8u << 20));
  bf16_t* w2t  = (bf16_t*)(ws + (24u << 20));
  bf16_t* hid  = (bf16_t*)(ws + (40u << 20));
  int*    idxw = (int*)(ws + (56u << 20));
  float*  ww   = (float*)(ws + (56u << 20) + 64);

  hipLaunchKernelGGL(prep_kernel, dim3(4096 + 1024 + 1), dim3(256), 0, stream,
                     x, dec, rw, rb, w1, w2, xb, w1t, w2t,
                     out + OFF_AUX, out + OFF_MASK, out + OFF_LOGITS, idxw, ww);
  hipLaunchKernelGGL(gemm1_kernel, dim3(8, 4, 16), dim3(256), 0, stream,
                     xb, w1t, b1, idxw, hid);
  hipLaunchKernelGGL(gemm2_kernel, dim3(8, 4, 8), dim3(512), 0, stream,
                     hid, w2t, b2, idxw, ww, out);
}

// Round 3
// 203.311 us; speedup vs baseline: 1.0899x; 1.0175x over previous
//
#include <hip/hip_runtime.h>
#include <hip/hip_bf16.h>
#include <stdint.h>

// Problem constants
#define EXP 8
#define DIM 1024
#define SEQL 512
#define BATCH 8
#define OUT_FINAL_N (BATCH * SEQL * DIM)   // 4194304
#define OFF_AUX    4194304
#define OFF_MASK   4194305
#define OFF_LOGITS 4194369

typedef __bf16 bf16_t;
typedef bf16_t bf16x8 __attribute__((ext_vector_type(8)));
typedef bf16_t bf16x4 __attribute__((ext_vector_type(4)));
typedef float  f32x4  __attribute__((ext_vector_type(4)));

typedef __attribute__((address_space(1))) void* as1p;
typedef __attribute__((address_space(3))) void* as3p;

__device__ __forceinline__ void glds16(const void* g, void* l) {
  // async global->LDS, 16B per lane; LDS dest = wave-uniform base + lane*16
  __builtin_amdgcn_global_load_lds((as1p)(void*)g, (as3p)l, 16, 0, 0);
}

// ---------------------------------------------------------------------------
// prep_kernel: fused { weight transpose-cast | x cast | router }.
// grid.x = 2048 (transpose 128k x 64n tiles) + 512 (x cast) + 1 (router).
// Transpose: fp32 LDS tile [n][k] (64 x 129, odd stride -> free write banks),
// written transposed (4 scalar ds_write per float4), read k-contiguous,
// cast at read, 256B-contiguous bf16x8 stores.
// ---------------------------------------------------------------------------
__global__ __launch_bounds__(256) void prep_kernel(
    const float* __restrict__ x, const float* __restrict__ dec,
    const float* __restrict__ rw, const float* __restrict__ rb,
    const float* __restrict__ w1, const float* __restrict__ w2,
    bf16_t* __restrict__ xb, bf16_t* __restrict__ w1t, bf16_t* __restrict__ w2t,
    float* __restrict__ out_aux, float* __restrict__ out_mask,
    float* __restrict__ out_logits, int* __restrict__ idx_ws,
    float* __restrict__ w_ws) {
  __shared__ float tile[64][129];    // 33024 B, [n][k] transposed tile
  __shared__ float part[256];
  __shared__ float lg64[64];
  __shared__ float probs[64];
  __shared__ float msk[64];
  const int bid = blockIdx.x;
  const int t = threadIdx.x;

  if (bid < 2048) {
    // ---- transpose-cast: matrix z, tile = 128 k-rows x 64 n-cols ----
    const int z = bid >> 7;              // 16 matrices
    const int rem = bid & 127;
    const int k0 = (rem >> 4) * 128;     // 8 k-tiles
    const int n0 = (rem & 15) * 64;      // 16 n-tiles
    const float* src = (z < 8) ? (w1 + (size_t)z * DIM * DIM)
                               : (w2 + (size_t)(z - 8) * DIM * DIM);
    bf16_t* dst = (z < 8) ? (w1t + (size_t)z * DIM * DIM)
                          : (w2t + (size_t)(z - 8) * DIM * DIM);
    const int rr = t >> 4, c4 = t & 15;
    // batched loads: 8 float4 in flight (128 B/thread)
    float4 v[8];
#pragma unroll
    for (int i = 0; i < 8; ++i)
      v[i] = *(const float4*)(src + (size_t)(k0 + rr + 16 * i) * DIM + n0 + c4 * 4);
    // scatter transposed into LDS: tile[n][k]
#pragma unroll
    for (int i = 0; i < 8; ++i) {
      const int k = rr + 16 * i;
      tile[c4 * 4 + 0][k] = v[i].x;
      tile[c4 * 4 + 1][k] = v[i].y;
      tile[c4 * 4 + 2][k] = v[i].z;
      tile[c4 * 4 + 3][k] = v[i].w;
    }
    __syncthreads();
    // read k-contiguous, cast, 16B stores (wave covers 4 x 256B rows/instr)
#pragma unroll
    for (int ii = 0; ii < 4; ++ii) {
      const int n = (t >> 4) + 16 * ii;
      const int c = t & 15;
      bf16x8 o;
#pragma unroll
      for (int wd = 0; wd < 8; ++wd) o[wd] = (bf16_t)tile[n][c * 8 + wd];
      *(bf16x8*)(dst + (size_t)(n0 + n) * DIM + k0 + c * 8) = o;
    }
  } else if (bid < 2048 + 512) {
    // ---- cast x: 1M float4s over 512 blocks, 8 per thread, batched ----
    const int i0 = (bid - 2048) * 2048 + t;
    float4 v[8];
#pragma unroll
    for (int i = 0; i < 8; ++i) v[i] = ((const float4*)x)[i0 + i * 256];
#pragma unroll
    for (int i = 0; i < 8; ++i) {
      bf16x4 o;
      o[0] = (bf16_t)v[i].x; o[1] = (bf16_t)v[i].y;
      o[2] = (bf16_t)v[i].z; o[3] = (bf16_t)v[i].w;
      ((bf16x4*)xb)[i0 + i * 256] = o;
    }
  } else {
    // ---- router ----
    const int p = t >> 2, seg = t & 3;
    const int b = p >> 3, e = p & 7;
    const float4* dv = (const float4*)(dec + b * DIM + seg * 256);
    const float4* wv = (const float4*)(rw + e * DIM + seg * 256);
    float s = 0.f;
#pragma unroll 8
    for (int i = 0; i < 64; ++i) {
      float4 a = dv[i], c = wv[i];
      s += a.x * c.x + a.y * c.y + a.z * c.z + a.w * c.w;
    }
    part[t] = s;
    __syncthreads();
    if (seg == 0) {
      float l = part[t] + part[t + 1] + part[t + 2] + part[t + 3] + rb[e];
      lg64[p] = l;
      out_logits[p] = l;
    }
    __syncthreads();
    if (t < 8) {
      float l[8];
      float mx = -1e30f;
#pragma unroll
      for (int k = 0; k < 8; ++k) { l[k] = lg64[t * 8 + k]; mx = fmaxf(mx, l[k]); }
      float pe[8];
      float sum = 0.f;
#pragma unroll
      for (int k = 0; k < 8; ++k) { pe[k] = expf(l[k] - mx); sum += pe[k]; }
      float inv = 1.f / sum;
#pragma unroll
      for (int k = 0; k < 8; ++k) { pe[k] *= inv; probs[t * 8 + k] = pe[k]; }
      int i0 = 0;
#pragma unroll
      for (int k = 1; k < 8; ++k) if (pe[k] > pe[i0]) i0 = k;
      int i1 = (i0 == 0) ? 1 : 0;
#pragma unroll
      for (int k = 0; k < 8; ++k) if (k != i0 && pe[k] > pe[i1]) i1 = k;
      float p0 = pe[i0], p1 = pe[i1];
      float invs = 1.f / (p0 + p1);
      idx_ws[t * 2] = i0;
      idx_ws[t * 2 + 1] = i1;
      w_ws[t * 2] = p0 * invs;
      w_ws[t * 2 + 1] = p1 * invs;
#pragma unroll
      for (int k = 0; k < 8; ++k) {
        float m = (k == i0 || k == i1) ? 1.f : 0.f;
        msk[t * 8 + k] = m;
        out_mask[t * 8 + k] = m;
      }
    }
    __syncthreads();
    if (t == 0) {
      float aux = 0.f;
#pragma unroll
      for (int k = 0; k < 8; ++k) {
        float mp = 0.f, mm = 0.f;
#pragma unroll
        for (int bb = 0; bb < 8; ++bb) { mp += probs[bb * 8 + k]; mm += msk[bb * 8 + k]; }
        aux += (mp * 0.125f) * (mm * 0.125f);
      }
      out_aux[0] = 8.f * aux;
    }
  }
}

// ---------------------------------------------------------------------------
// Double-buffered MFMA K-loop, 64x128 tile, 4 waves (wave = 32x64 = 2x4
// mfma_f32_16x16x32_bf16).  A (64,K) K-major, Bt (128-col slice, K-major).
// LDS: sA = 2 x 4096 B, sB = 2 x 8192 B.  XOR-swizzled 16B chunks.
// Barrier-at-top + prefetch-after-barrier: the vmcnt(0) drain at the NEXT
// barrier overlaps with this iteration's MFMA+ds_read work.
// ---------------------------------------------------------------------------
__device__ __forceinline__ void kloop_64x128(const bf16_t* __restrict__ A,
                                             const bf16_t* __restrict__ Bt,
                                             char* sA, char* sB, int t,
                                             f32x4 acc[2][4]) {
  const int lane = t & 63;
  const int w = t >> 6, wr = w >> 1, wc = w & 1;
  const int m15 = lane & 15, q = lane >> 4;
  const int rl = t >> 2, cp = (t & 3) ^ (rl & 3);
  const bf16_t* ga  = A  + (size_t)rl * DIM + cp * 8;
  const bf16_t* gb0 = Bt + (size_t)rl * DIM + cp * 8;
  const bf16_t* gb1 = gb0 + (size_t)64 * DIM;

  const char* ra[2];
  const char* rb[4];
#pragma unroll
  for (int i = 0; i < 2; ++i) {
    const int r = wr * 32 + i * 16 + m15;
    ra[i] = sA + r * 64 + ((q ^ (r & 3)) * 16);
  }
#pragma unroll
  for (int j = 0; j < 4; ++j) {
    const int n = wc * 64 + j * 16 + m15;
    rb[j] = sB + n * 64 + ((q ^ (n & 3)) * 16);
  }

  // prologue: stage k-tile 0 into buffer 0
  glds16(ga,  sA + t * 16);
  glds16(gb0, sB + t * 16);
  glds16(gb1, sB + 4096 + t * 16);

  for (int kt = 0; kt < 32; ++kt) {
    const int cur = kt & 1;
    __syncthreads();                    // drains stage(kt); prev reads retired
    if (kt < 31) {                      // prefetch kt+1 into other buffer
      const int nxt = cur ^ 1;
      const int off = (kt + 1) * 32;
      glds16(ga + off,  sA + nxt * 4096 + t * 16);
      glds16(gb0 + off, sB + nxt * 8192 + t * 16);
      glds16(gb1 + off, sB + nxt * 8192 + 4096 + t * 16);
    }
    bf16x8 af[2], bfr[4];
#pragma unroll
    for (int i = 0; i < 2; ++i) af[i] = *(const bf16x8*)(ra[i] + cur * 4096);
#pragma unroll
    for (int j = 0; j < 4; ++j) bfr[j] = *(const bf16x8*)(rb[j] + cur * 8192);
#pragma unroll
    for (int i = 0; i < 2; ++i)
#pragma unroll
      for (int j = 0; j < 4; ++j)
        acc[i][j] = __builtin_amdgcn_mfma_f32_16x16x32_bf16(af[i], bfr[j], acc[i][j], 0, 0, 0);
  }
}

// ---------------------------------------------------------------------------
// GEMM1: hidden[slot] = relu(x[b] @ w1[e] + b1[e]), bf16 out via LDS bounce.
// grid (8 N, 8 M, 16 slots) = 1024 blocks, 256 thr, 4 blocks/CU target.
// ---------------------------------------------------------------------------
__global__ __launch_bounds__(256, 4) void gemm1_kernel(const bf16_t* __restrict__ xb,
                                                       const bf16_t* __restrict__ w1t,
                                                       const float* __restrict__ b1,
                                                       const int* __restrict__ topk_idx,
                                                       bf16_t* __restrict__ hidden) {
  __shared__ __align__(16) char smem[24576];
  const int tid = threadIdx.x;
  const int bN = blockIdx.x, bM = blockIdx.y, slot = blockIdx.z;
  const int b = slot >> 1;
  const int e = topk_idx[slot];

  const bf16_t* A  = xb + ((size_t)b * SEQL + bM * 64) * DIM;
  const bf16_t* Bt = w1t + ((size_t)e * DIM + bN * 128) * DIM;

  f32x4 acc[2][4];
#pragma unroll
  for (int i = 0; i < 2; ++i)
#pragma unroll
    for (int j = 0; j < 4; ++j) acc[i][j] = {0.f, 0.f, 0.f, 0.f};

  kloop_64x128(A, Bt, smem, smem + 8192, tid, acc);

  // epilogue: bias + relu + cast, bounce through LDS for 16B stores.
  // C/D layout: col = lane&15, row = quad*4 + reg (m89-verified).
  __syncthreads();                       // staging reads done; reuse smem
  bf16_t* hb = (bf16_t*)smem;            // [64][136] halfwords (272B rows, 16B-aligned)
  const int lane = tid & 63, w = tid >> 6;
  const int wr = w >> 1, wc = w & 1;
  const int m15 = lane & 15, q = lane >> 4;
  const float* be = b1 + e * DIM;
#pragma unroll
  for (int i = 0; i < 2; ++i)
#pragma unroll
    for (int j = 0; j < 4; ++j) {
      const int colL = wc * 64 + j * 16 + m15;
      const float bias = be[bN * 128 + colL];
#pragma unroll
      for (int r = 0; r < 4; ++r) {
        const int rowL = wr * 32 + i * 16 + q * 4 + r;
        hb[rowL * 136 + colL] = (bf16_t)fmaxf(acc[i][j][r] + bias, 0.f);
      }
    }
  __syncthreads();
  bf16_t* H = hidden + (size_t)slot * SEQL * DIM + ((size_t)bM * 64) * DIM + bN * 128;
#pragma unroll
  for (int ii = 0; ii < 4; ++ii) {
    const int r = (tid >> 4) + 16 * ii;
    const int c = tid & 15;
    bf16x8 vv = *(const bf16x8*)(hb + r * 136 + c * 8);
    *(bf16x8*)(H + (size_t)r * DIM + c * 8) = vv;
  }
}

// ---------------------------------------------------------------------------
// GEMM2: out[b] = w0*(h0 @ w2[e0]) + w1*(h1 @ w2[e1]) + combined bias, fp32.
// 512 thr = 2 expert groups x 4 waves, each group a 64x128 tile.
// grid (8 N, 8 M, 8 b) = 512 blocks (2/CU).  Combine via LDS scratch.
// ---------------------------------------------------------------------------
__global__ __launch_bounds__(512, 4) void gemm2_kernel(const bf16_t* __restrict__ hidden,
                                                       const bf16_t* __restrict__ w2t,
                                                       const float* __restrict__ b2,
                                                       const int* __restrict__ topk_idx,
                                                       const float* __restrict__ topk_w,
                                                       float* __restrict__ out) {
  __shared__ __align__(16) char smem[49152];
  const int tid = threadIdx.x;
  const int g = tid >> 8;        // expert slot group
  const int t = tid & 255;       // index within group
  const int bN = blockIdx.x, bM = blockIdx.y, b = blockIdx.z;
  const int e = topk_idx[b * 2 + g];
  const float sg = topk_w[b * 2 + g];

  char* sA = smem + g * 24576;
  char* sB = smem + g * 24576 + 8192;

  f32x4 acc[2][4];
#pragma unroll
  for (int i = 0; i < 2; ++i)
#pragma unroll
    for (int j = 0; j < 4; ++j) acc[i][j] = {0.f, 0.f, 0.f, 0.f};

  const bf16_t* A  = hidden + ((size_t)(b * 2 + g) * SEQL + bM * 64) * DIM;
  const bf16_t* Bt = w2t + ((size_t)e * DIM + bN * 128) * DIM;
  kloop_64x128(A, Bt, sA, sB, t, acc);

  // ---- combine: group1 -> LDS -> group0 adds + biases + store ----
  __syncthreads();               // all staging reads done; smem reusable
  float* scr = (float*)smem;     // 16 KB per half, stride-256 (bank = t%32)
  const int lane = t & 63, wv = t >> 6;
  const int wr = wv >> 1, wc = wv & 1;
  const int m15 = lane & 15, q = lane >> 4;
  const float w0 = topk_w[b * 2], w1v = topk_w[b * 2 + 1];
  const float* be0 = b2 + topk_idx[b * 2] * DIM;
  const float* be1 = b2 + topk_idx[b * 2 + 1] * DIM;
  float* O = out + (size_t)b * SEQL * DIM;

#pragma unroll
  for (int half = 0; half < 2; ++half) {
    if (g == 1) {
#pragma unroll
      for (int j = 0; j < 4; ++j)
#pragma unroll
        for (int r = 0; r < 4; ++r)
          scr[(j * 4 + r) * 256 + t] = sg * acc[half][j][r];
    }
    __syncthreads();
    if (g == 0) {
#pragma unroll
      for (int j = 0; j < 4; ++j) {
        const int col = bN * 128 + wc * 64 + j * 16 + m15;
        const float bb = w0 * be0[col] + w1v * be1[col];
        const int row = bM * 64 + wr * 32 + half * 16 + q * 4;
#pragma unroll
        for (int r = 0; r < 4; ++r)
          O[(size_t)(row + r) * DIM + col] =
              sg * acc[half][j][r] + scr[(j * 4 + r) * 256 + t] + bb;
      }
    }
    __syncthreads();
  }
}

// ---------------------------------------------------------------------------
extern "C" void kernel_launch(void* const* d_in, const int* in_sizes, int n_in,
                              void* d_out, int out_size, void* d_ws, size_t ws_size,
                              hipStream_t stream) {
  const float* x   = (const float*)d_in[0];
  const float* dec = (const float*)d_in[1];
  const float* rw  = (const float*)d_in[2];
  const float* rb  = (const float*)d_in[3];
  const float* w1  = (const float*)d_in[4];
  const float* w2  = (const float*)d_in[5];
  const float* b1  = (const float*)d_in[6];
  const float* b2  = (const float*)d_in[7];
  float* out = (float*)d_out;

  // ws layout: xb 8MB | w1t 16MB | w2t 16MB | hidden 16MB | router scratch
  char* ws = (char*)d_ws;
  bf16_t* xb   = (bf16_t*)(ws);
  bf16_t* w1t  = (bf16_t*)(ws + (8u << 20));
  bf16_t* w2t  = (bf16_t*)(ws + (24u << 20));
  bf16_t* hid  = (bf16_t*)(ws + (40u << 20));
  int*    idxw = (int*)(ws + (56u << 20));
  float*  ww   = (float*)(ws + (56u << 20) + 64);

  hipLaunchKernelGGL(prep_kernel, dim3(2048 + 512 + 1), dim3(256), 0, stream,
                     x, dec, rw, rb, w1, w2, xb, w1t, w2t,
                     out + OFF_AUX, out + OFF_MASK, out + OFF_LOGITS, idxw, ww);
  hipLaunchKernelGGL(gemm1_kernel, dim3(8, 8, 16), dim3(256), 0, stream,
                     xb, w1t, b1, idxw, hid);
  hipLaunchKernelGGL(gemm2_kernel, dim3(8, 8, 8), dim3(512), 0, stream,
                     hid, w2t, b2, idxw, ww, out);
}